// Round 8
// baseline (685.257 us; speedup 1.0000x reference)
//
#include <hip/hip_runtime.h>
#include <hip/hip_bf16.h>

#define NUM_GRAPHS 64
#define NODES 256
#define EDGES 1024
#define NTOT (NUM_GRAPHS * NODES) /* 16384 */
#define DF 512
#define HF 1024
#define HP 256
#define NC 10

// monotone order-preserving encode/decode for fp32 (bijection, works for +/-)
__device__ __forceinline__ unsigned encf(float x) {
    union { float f; unsigned u; } c; c.f = x;
    return (c.u & 0x80000000u) ? ~c.u : (c.u | 0x80000000u);
}
__device__ __forceinline__ float decf(unsigned e) {
    union { float f; unsigned u; } c;
    c.u = (e & 0x80000000u) ? (e & 0x7fffffffu) : ~e;
    return c.f;
}

// ---------------- Stage 1: f = sigmoid(relu(x@W1+b1)@w2 + b2) --------------
// thread owns hidden units j = tid + 256*q (q<4); h[n][q] in registers;
// w1 streamed coalesced once per block.
#define TN2 16
__global__ __launch_bounds__(256) void k_fil(
    const float* __restrict__ x, const float* __restrict__ w1,
    const float* __restrict__ b1, const float* __restrict__ w2,
    const float* __restrict__ b2, float* __restrict__ fout)
{
    __shared__ float xs[TN2][DF];   // 32 KB
    __shared__ float part[256];
    const int tid = threadIdx.x;
    const int n0 = blockIdx.x * TN2;

    for (int c = tid; c < TN2 * DF / 4; c += 256) {
        int n = c >> 7, k4 = (c & 127) << 2;
        *(float4*)&xs[n][k4] = *(const float4*)(x + (size_t)(n0 + n) * DF + k4);
    }
    __syncthreads();

    float h[TN2][4];
#pragma unroll
    for (int n = 0; n < TN2; ++n)
#pragma unroll
        for (int q = 0; q < 4; ++q) h[n][q] = 0.f;

    for (int k = 0; k < DF; ++k) {
        float wr[4];
#pragma unroll
        for (int q = 0; q < 4; ++q) wr[q] = w1[(size_t)k * HF + tid + 256 * q];
#pragma unroll
        for (int n = 0; n < TN2; ++n) {
            float xv = xs[n][k];
#pragma unroll
            for (int q = 0; q < 4; ++q) h[n][q] = fmaf(xv, wr[q], h[n][q]);
        }
    }

    float b1r[4], w2r[4];
#pragma unroll
    for (int q = 0; q < 4; ++q) {
        b1r[q] = b1[tid + 256 * q];
        w2r[q] = w2[tid + 256 * q];
    }
    const float b2v = b2[0];

    for (int n = 0; n < TN2; ++n) {
        float s = 0.f;
#pragma unroll
        for (int q = 0; q < 4; ++q) {
            float hv = h[n][q] + b1r[q];
            s += (hv > 0.f ? hv : 0.f) * w2r[q];
        }
        part[tid] = s;
        __syncthreads();
        for (int off = 128; off > 0; off >>= 1) {
            if (tid < off) part[tid] += part[tid + off];
            __syncthreads();
        }
        if (tid == 0) fout[n0 + n] = 1.f / (1.f + expf(-(part[0] + b2v)));
        __syncthreads();
    }
}

// ------------- Stage 2: 0-dim persistence, literal port of reference ------
// Sort EDGES by (w = max(f_u,f_v), edge_idx) [== stable jnp argsort], then
// serial union-find replay exactly as the reference body(). Unpaired ->
// component max (extended persistence), per reference.
__global__ __launch_bounds__(256) void k_pers(
    const int* __restrict__ edges, const float* __restrict__ fbuf,
    float* __restrict__ dout /* [2][NTOT] */)
{
    const int bid = blockIdx.x;
    const int g = bid >> 1, sgn = bid & 1;
    const int tid = threadIdx.x;
    __shared__ float fv[NODES];
    __shared__ unsigned long long ekey[EDGES];  // (encf(w)<<32) | edge_idx
    __shared__ int uv_[EDGES];                  // u | (v<<8)
    __shared__ int par[NODES];
    __shared__ float death[NODES];
    __shared__ unsigned char paired[NODES];
    __shared__ unsigned cmax[NODES];

    float f0 = fbuf[g * NODES + tid];
    fv[tid] = sgn ? -f0 : f0;
    par[tid] = tid; death[tid] = 0.f; paired[tid] = 0; cmax[tid] = 0u;
    __syncthreads();

#pragma unroll
    for (int q = 0; q < 4; ++q) {
        int e = tid + q * 256;
        int u = edges[2 * (g * EDGES + e)]     - g * NODES;
        int v = edges[2 * (g * EDGES + e) + 1] - g * NODES;
        float w = fmaxf(fv[u], fv[v]);
        ekey[e] = ((unsigned long long)encf(w) << 32) | (unsigned)e;
        uv_[e] = u | (v << 8);
    }
    __syncthreads();

    // bitonic sort of 1024 edge keys, ascending (stable via idx in low bits)
    for (int k = 2; k <= EDGES; k <<= 1) {
        for (int j = k >> 1; j > 0; j >>= 1) {
            for (int t = tid; t < EDGES; t += 256) {
                int txj = t ^ j;
                if (txj > t) {
                    unsigned long long a = ekey[t], b = ekey[txj];
                    bool up = ((t & k) == 0);
                    if ((a > b) == up) { ekey[t] = b; ekey[txj] = a; }
                }
            }
            __syncthreads();
        }
    }

    // serial replay, literal translation of the reference body()
    if (tid == 0) {
        for (int s = 0; s < EDGES; ++s) {
            unsigned long long kk = ekey[s];
            int e = (int)(kk & 0xFFFFFFFFULL);
            int u = uv_[e] & 255, v = (uv_[e] >> 8) & 255;
            float w = decf((unsigned)(kk >> 32));
            int ru = u; while (par[ru] != ru) { par[ru] = par[par[ru]]; ru = par[ru]; }
            int rv = v; while (par[rv] != rv) { par[rv] = par[par[rv]]; rv = par[rv]; }
            par[u] = ru; par[v] = rv;
            if (ru != rv) {
                bool ue = (fv[ru] < fv[rv]) || ((fv[ru] == fv[rv]) && (ru < rv));
                int eld = ue ? ru : rv, yng = ue ? rv : ru;
                par[yng] = eld;
                death[yng] = w;
                paired[yng] = 1;
            }
        }
    }
    __syncthreads();

    // component max over final components, then select per reference
    int r = tid;
    while (par[r] != r) r = par[r];
    atomicMax(&cmax[r], encf(fv[tid]));
    __syncthreads();
    dout[sgn * NTOT + g * NODES + tid] = paired[tid] ? death[tid] : decf(cmax[r]);
}

// ------- Stage 3: per-pair MLPs + segment sum + linear head (fused) -------
__global__ __launch_bounds__(256) void k_head(
    const float* __restrict__ fbuf, const float* __restrict__ dbuf,
    const float* __restrict__ wp0, const float* __restrict__ bp0,
    const float* __restrict__ wp1, const float* __restrict__ bp1,
    const float* __restrict__ wh, const float* __restrict__ bh,
    float* __restrict__ out)
{
    const int g = blockIdx.x, tid = threadIdx.x;
    __shared__ float lf[NODES], l0[NODES], l1[NODES];
    __shared__ float sp0[NODES], sp1[NODES];
    lf[tid] = fbuf[g * NODES + tid];
    l0[tid] = dbuf[g * NODES + tid];
    l1[tid] = dbuf[NTOT + g * NODES + tid];
    __syncthreads();
    // thread = hidden unit j of H_PHI
    const float w00 = wp0[tid], w01 = wp0[HP + tid], bb0 = bp0[tid];
    const float w10 = wp1[tid], w11 = wp1[HP + tid], bb1 = bp1[tid];
    float s0 = 0.f, s1 = 0.f;
    for (int n = 0; n < NODES; ++n) {
        float f = lf[n], d0 = l0[n], d1 = l1[n];
        float a0 = fmaf(f, w00, fmaf(d0, w01, bb0));      // h0 = (f, d_sub)
        float a1 = fmaf(-d1, w10, fmaf(f, w11, bb1));     // h1 = (-d_sup, f)
        s0 += a0 > 0.f ? a0 : 0.f;
        s1 += a1 > 0.f ? a1 : 0.f;
    }
    sp0[tid] = s0; sp1[tid] = s1;
    __syncthreads();
    if (tid < NC) {
        float acc = bh[tid];
        for (int j = 0; j < HP; ++j)
            acc += sp0[j] * wh[j * NC + tid] + sp1[j] * wh[(HP + j) * NC + tid];
        out[g * NC + tid] = acc;   // OUTPUT IS FLOAT32 (reference dtype)
    }
}

extern "C" void kernel_launch(void* const* d_in, const int* in_sizes, int n_in,
                              void* d_out, int out_size, void* d_ws, size_t ws_size,
                              hipStream_t stream)
{
    const float* x   = (const float*)d_in[0];
    const int*   edg = (const int*)d_in[1];
    // d_in[2] = sample_id: unused (nodes are block-contiguous per graph)
    const float* w1  = (const float*)d_in[3];
    const float* b1  = (const float*)d_in[4];
    const float* w2  = (const float*)d_in[5];
    const float* b2  = (const float*)d_in[6];
    const float* wp0 = (const float*)d_in[7];
    const float* bp0 = (const float*)d_in[8];
    const float* wp1 = (const float*)d_in[9];
    const float* bp1 = (const float*)d_in[10];
    const float* wh  = (const float*)d_in[11];
    const float* bh  = (const float*)d_in[12];

    float* fbuf = (float*)d_ws;          // [NTOT]
    float* dbuf = fbuf + NTOT;           // [2][NTOT]

    k_fil <<<NTOT / TN2, 256, 0, stream>>>(x, w1, b1, w2, b2, fbuf);
    k_pers<<<NUM_GRAPHS * 2, 256, 0, stream>>>(edg, fbuf, dbuf);
    k_head<<<NUM_GRAPHS, 256, 0, stream>>>(fbuf, dbuf, wp0, bp0, wp1, bp1, wh, bh,
                                           (float*)d_out);
}

// Round 9
// 395.923 us; speedup vs baseline: 1.7308x; 1.7308x over previous
//
#include <hip/hip_runtime.h>
#include <hip/hip_bf16.h>

#define NUM_GRAPHS 64
#define NODES 256
#define EDGES 1024
#define NTOT (NUM_GRAPHS * NODES) /* 16384 */
#define DF 512
#define HF 1024
#define HP 256
#define NC 10
#define INF32 0xFFFFFFFFu

// monotone order-preserving encode for fp32 (bijection, works for +/-)
__device__ __forceinline__ unsigned encf(float x) {
    union { float f; unsigned u; } c; c.f = x;
    return (c.u & 0x80000000u) ? ~c.u : (c.u | 0x80000000u);
}

// ---------------- Stage 1: f = sigmoid(relu(x@W1+b1)@w2 + b2) --------------
// (unchanged from green R8 baseline)
#define TN2 16
__global__ __launch_bounds__(256) void k_fil(
    const float* __restrict__ x, const float* __restrict__ w1,
    const float* __restrict__ b1, const float* __restrict__ w2,
    const float* __restrict__ b2, float* __restrict__ fout)
{
    __shared__ float xs[TN2][DF];   // 32 KB
    __shared__ float part[256];
    const int tid = threadIdx.x;
    const int n0 = blockIdx.x * TN2;

    for (int c = tid; c < TN2 * DF / 4; c += 256) {
        int n = c >> 7, k4 = (c & 127) << 2;
        *(float4*)&xs[n][k4] = *(const float4*)(x + (size_t)(n0 + n) * DF + k4);
    }
    __syncthreads();

    float h[TN2][4];
#pragma unroll
    for (int n = 0; n < TN2; ++n)
#pragma unroll
        for (int q = 0; q < 4; ++q) h[n][q] = 0.f;

    for (int k = 0; k < DF; ++k) {
        float wr[4];
#pragma unroll
        for (int q = 0; q < 4; ++q) wr[q] = w1[(size_t)k * HF + tid + 256 * q];
#pragma unroll
        for (int n = 0; n < TN2; ++n) {
            float xv = xs[n][k];
#pragma unroll
            for (int q = 0; q < 4; ++q) h[n][q] = fmaf(xv, wr[q], h[n][q]);
        }
    }

    float b1r[4], w2r[4];
#pragma unroll
    for (int q = 0; q < 4; ++q) {
        b1r[q] = b1[tid + 256 * q];
        w2r[q] = w2[tid + 256 * q];
    }
    const float b2v = b2[0];

    for (int n = 0; n < TN2; ++n) {
        float s = 0.f;
#pragma unroll
        for (int q = 0; q < 4; ++q) {
            float hv = h[n][q] + b1r[q];
            s += (hv > 0.f ? hv : 0.f) * w2r[q];
        }
        part[tid] = s;
        __syncthreads();
        for (int off = 128; off > 0; off >>= 1) {
            if (tid < off) part[tid] += part[tid + off];
            __syncthreads();
        }
        if (tid == 0) fout[n0 + n] = 1.f / (1.f + expf(-(part[0] + b2v)));
        __syncthreads();
    }
}

// ------------- Stage 2: 0-dim persistence via Boruvka MST filter ----------
// Rank domain: vertices sorted by (encf(f), idx); edge weight = max endpoint
// rank, key = (rhi<<18)|(e<<8)|rlo (unique, == reference (w, e) order up to
// value-equal ties, which leave death VALUES invariant). Only MST edges ever
// merge (unique keys -> unique MST): find them in parallel (Boruvka), then
// serially replay only those <=255 edges.
__global__ __launch_bounds__(256) void k_pers(
    const int* __restrict__ edges, const float* __restrict__ fbuf,
    float* __restrict__ dout /* [2][NTOT] */)
{
    const int bid = blockIdx.x;
    const int g = bid >> 1, sgn = bid & 1;
    const int tid = threadIdx.x;

    __shared__ float fv[NODES];
    __shared__ unsigned long long vkey[NODES];
    __shared__ int order_[NODES], rank_[NODES];
    __shared__ float fvr[NODES];
    __shared__ unsigned eks[EDGES];
    __shared__ int comp[NODES];
    __shared__ unsigned minE[NODES];
    __shared__ int nxt[NODES], par2[NODES];
    __shared__ unsigned char mstflag[EDGES];
    __shared__ int cnt;
    __shared__ unsigned mstK[NODES];
    __shared__ int par[NODES], dr[NODES], cmaxr[NODES];

    float f0 = fbuf[g * NODES + tid];
    fv[tid] = sgn ? -f0 : f0;
    vkey[tid] = ((unsigned long long)encf(fv[tid]) << 32) | (unsigned)tid;
    __syncthreads();

    // bitonic sort 256 vertex keys ascending
    for (int k = 2; k <= NODES; k <<= 1)
        for (int j = k >> 1; j > 0; j >>= 1) {
            int i = tid, ixj = i ^ j;
            if (ixj > i) {
                unsigned long long a = vkey[i], b = vkey[ixj];
                bool up = ((i & k) == 0);
                if ((a > b) == up) { vkey[i] = b; vkey[ixj] = a; }
            }
            __syncthreads();
        }

    int ov = (int)(unsigned)(vkey[tid] & 0xFFFFFFFFULL);
    order_[tid] = ov;
    rank_[ov] = tid;
    fvr[tid] = fv[ov];
    comp[tid] = tid;
    __syncthreads();

    // edge keys in rank domain; self-loops -> INF
#pragma unroll
    for (int q = 0; q < 4; ++q) {
        int e = tid + q * 256;
        int u = edges[2 * (g * EDGES + e)]     - g * NODES;
        int v = edges[2 * (g * EDGES + e) + 1] - g * NODES;
        if (u == v) { eks[e] = INF32; }
        else {
            int ra = rank_[u], rb = rank_[v];
            int rlo = ra < rb ? ra : rb, rhi = ra < rb ? rb : ra;
            eks[e] = ((unsigned)rhi << 18) | ((unsigned)e << 8) | (unsigned)rlo;
        }
        mstflag[e] = 0;
    }
    __syncthreads();

    // Boruvka: 8 rounds (components at least halve per round)
    for (int round = 0; round < 8; ++round) {
        minE[tid] = INF32;
        __syncthreads();
#pragma unroll
        for (int q = 0; q < 4; ++q) {
            unsigned k = eks[tid + q * 256];
            if (k != INF32) {
                int rlo = (int)(k & 255u), rhi = (int)(k >> 18);
                int cu = comp[rlo], cv = comp[rhi];
                if (cu != cv) {
                    atomicMin(&minE[cu], k);
                    atomicMin(&minE[cv], k);
                }
            }
        }
        __syncthreads();
        // hooking: each root with an outgoing min edge points to the other side
        {
            unsigned mk = minE[tid];
            int o = tid;
            if (mk != INF32) {
                int rlo = (int)(mk & 255u), rhi = (int)(mk >> 18);
                int cu = comp[rlo], cv = comp[rhi];
                o = (cu == tid) ? cv : cu;
                mstflag[(mk >> 8) & 0x3FFu] = 1;   // cut property: MST edge
            }
            nxt[tid] = o;
        }
        __syncthreads();
        // resolve mutual 2-cycles (unique keys -> only 2-cycles), keep min id
        {
            int o = nxt[tid];
            int p = o;
            if (nxt[o] == tid && tid < o) p = tid;
            par2[tid] = p;
        }
        __syncthreads();
        // pointer jumping to full depth (<=256 chain -> 8 doublings)
        for (int j = 0; j < 8; ++j) {
            int p = par2[par2[tid]];
            __syncthreads();
            par2[tid] = p;
            __syncthreads();
        }
        comp[tid] = par2[comp[tid]];
        __syncthreads();
    }

    // collect MST edges (<=255)
    if (tid == 0) cnt = 0;
    __syncthreads();
#pragma unroll
    for (int q = 0; q < 4; ++q) {
        int e = tid + q * 256;
        if (mstflag[e]) {
            int p = atomicAdd(&cnt, 1);
            mstK[p] = eks[e];
        }
    }
    __syncthreads();
    if (tid >= cnt) mstK[tid] = INF32;
    __syncthreads();

    // bitonic sort 256 u32 MST keys ascending
    for (int k = 2; k <= NODES; k <<= 1)
        for (int j = k >> 1; j > 0; j >>= 1) {
            int i = tid, ixj = i ^ j;
            if (ixj > i) {
                unsigned a = mstK[i], b = mstK[ixj];
                bool up = ((i & k) == 0);
                if ((a > b) == up) { mstK[i] = b; mstK[ixj] = a; }
            }
            __syncthreads();
        }

    par[tid] = tid; dr[tid] = -1; cmaxr[tid] = 0;
    __syncthreads();

    // serial Kruskal replay over sorted MST edges only (rank domain:
    // elder = smaller rank == smaller (f, idx), death = fvr[rhi] = w)
    if (tid == 0) {
        for (int s = 0; s < NODES; ++s) {
            unsigned k = mstK[s];
            if (k == INF32) break;
            int rlo = (int)(k & 255u), rhi = (int)(k >> 18);
            int a = rlo; while (par[a] != a) { par[a] = par[par[a]]; a = par[a]; }
            int b = rhi; while (par[b] != b) { par[b] = par[par[b]]; b = par[b]; }
            if (a != b) {
                int elder = a < b ? a : b, young = a < b ? b : a;
                par[young] = elder;
                dr[young] = rhi;
            }
        }
    }
    __syncthreads();

    // component max (extended persistence for unpaired roots)
    int r = tid;
    while (par[r] != r) r = par[r];
    atomicMax(&cmaxr[r], tid);
    __syncthreads();

    float dv = (dr[tid] >= 0) ? fvr[dr[tid]] : fvr[cmaxr[r]];
    dout[sgn * NTOT + g * NODES + order_[tid]] = dv;
}

// ------- Stage 3: per-pair MLPs + segment sum + linear head (fused) -------
__global__ __launch_bounds__(256) void k_head(
    const float* __restrict__ fbuf, const float* __restrict__ dbuf,
    const float* __restrict__ wp0, const float* __restrict__ bp0,
    const float* __restrict__ wp1, const float* __restrict__ bp1,
    const float* __restrict__ wh, const float* __restrict__ bh,
    float* __restrict__ out)
{
    const int g = blockIdx.x, tid = threadIdx.x;
    __shared__ float lf[NODES], l0[NODES], l1[NODES];
    __shared__ float sp0[NODES], sp1[NODES];
    lf[tid] = fbuf[g * NODES + tid];
    l0[tid] = dbuf[g * NODES + tid];
    l1[tid] = dbuf[NTOT + g * NODES + tid];
    __syncthreads();
    const float w00 = wp0[tid], w01 = wp0[HP + tid], bb0 = bp0[tid];
    const float w10 = wp1[tid], w11 = wp1[HP + tid], bb1 = bp1[tid];
    float s0 = 0.f, s1 = 0.f;
    for (int n = 0; n < NODES; ++n) {
        float f = lf[n], d0 = l0[n], d1 = l1[n];
        float a0 = fmaf(f, w00, fmaf(d0, w01, bb0));      // h0 = (f, d_sub)
        float a1 = fmaf(-d1, w10, fmaf(f, w11, bb1));     // h1 = (-d_sup, f)
        s0 += a0 > 0.f ? a0 : 0.f;
        s1 += a1 > 0.f ? a1 : 0.f;
    }
    sp0[tid] = s0; sp1[tid] = s1;
    __syncthreads();
    if (tid < NC) {
        float acc = bh[tid];
        for (int j = 0; j < HP; ++j)
            acc += sp0[j] * wh[j * NC + tid] + sp1[j] * wh[(HP + j) * NC + tid];
        out[g * NC + tid] = acc;   // f32 output (reference dtype)
    }
}

extern "C" void kernel_launch(void* const* d_in, const int* in_sizes, int n_in,
                              void* d_out, int out_size, void* d_ws, size_t ws_size,
                              hipStream_t stream)
{
    const float* x   = (const float*)d_in[0];
    const int*   edg = (const int*)d_in[1];
    // d_in[2] = sample_id: unused (nodes are block-contiguous per graph)
    const float* w1  = (const float*)d_in[3];
    const float* b1  = (const float*)d_in[4];
    const float* w2  = (const float*)d_in[5];
    const float* b2  = (const float*)d_in[6];
    const float* wp0 = (const float*)d_in[7];
    const float* bp0 = (const float*)d_in[8];
    const float* wp1 = (const float*)d_in[9];
    const float* bp1 = (const float*)d_in[10];
    const float* wh  = (const float*)d_in[11];
    const float* bh  = (const float*)d_in[12];

    float* fbuf = (float*)d_ws;          // [NTOT]
    float* dbuf = fbuf + NTOT;           // [2][NTOT]

    k_fil <<<NTOT / TN2, 256, 0, stream>>>(x, w1, b1, w2, b2, fbuf);
    k_pers<<<NUM_GRAPHS * 2, 256, 0, stream>>>(edg, fbuf, dbuf);
    k_head<<<NUM_GRAPHS, 256, 0, stream>>>(fbuf, dbuf, wp0, bp0, wp1, bp1, wh, bh,
                                           (float*)d_out);
}

// Round 10
// 274.511 us; speedup vs baseline: 2.4963x; 1.4423x over previous
//
#include <hip/hip_runtime.h>
#include <hip/hip_bf16.h>

#define NUM_GRAPHS 64
#define NODES 256
#define EDGES 1024
#define NTOT (NUM_GRAPHS * NODES) /* 16384 */
#define DF 512
#define HF 1024
#define HP 256
#define NC 10
#define INF32 0xFFFFFFFFu

typedef short bf16x8 __attribute__((ext_vector_type(8)));
typedef float f32x4 __attribute__((ext_vector_type(4)));

__device__ __forceinline__ unsigned short bf16r(float f) {
    __hip_bfloat16 h = __float2bfloat16(f);
    return *(unsigned short*)&h;
}
// monotone order-preserving encode for fp32 (bijection, works for +/-)
__device__ __forceinline__ unsigned encf(float x) {
    union { float f; unsigned u; } c; c.f = x;
    return (c.u & 0x80000000u) ? ~c.u : (c.u | 0x80000000u);
}

// ---- w1 (f32 [k][j]) -> w1bT (bf16 [j][k]) transpose+convert, LDS tiled ---
__global__ __launch_bounds__(256) void k_cvtT(
    const float* __restrict__ w1, unsigned short* __restrict__ w1bT)
{
    __shared__ unsigned short t[32][33];
    const int jt = blockIdx.x & 31, kt = blockIdx.x >> 5;   // 32 x 16 tiles
    const int tx = threadIdx.x & 31, ty = threadIdx.x >> 5; // 32 x 8
    for (int r = ty; r < 32; r += 8)
        t[r][tx] = bf16r(w1[(size_t)(kt * 32 + r) * HF + jt * 32 + tx]);
    __syncthreads();
    for (int r = ty; r < 32; r += 8)
        w1bT[(size_t)(jt * 32 + r) * DF + kt * 32 + tx] = t[tx][r];
}

// ------------- Stage 1 (MFMA): f = sigmoid(relu(x@W1+b1)@w2 + b2) ---------
// 512 blocks x 32 nodes. Wave w owns hidden cols [256w, 256w+256); 16x16x32
// bf16 MFMA, fp32 accum; relu+w2 fused per 16x16 tile; shfl+LDS reduce.
#define XPAD 8
#define XROW (DF + XPAD)   /* 520 bf16: stride 1040 B -> 2-way banks (free) */
__global__ __launch_bounds__(256) void k_fil_mfma(
    const float* __restrict__ x, const unsigned short* __restrict__ w1bT,
    const float* __restrict__ b1, const float* __restrict__ w2,
    const float* __restrict__ b2, float* __restrict__ fout)
{
    __shared__ unsigned short xs[32 * XROW];  // 33.3 KB
    __shared__ float facc[32];
    const int tid = threadIdx.x;
    const int lane = tid & 63;
    const int wv = tid >> 6;          // wave 0..3
    const int l15 = lane & 15;
    const int quad = lane >> 4;       // 0..3
    const int n0 = blockIdx.x * 32;

    // stage + convert x tile (32 nodes x 512 feats) f32 -> bf16 LDS
    for (int c = tid; c < 32 * DF / 4; c += 256) {
        int n = c >> 7, k4 = (c & 127) << 2;
        float4 v = *(const float4*)(x + (size_t)(n0 + n) * DF + k4);
        unsigned short* d = &xs[n * XROW + k4];
        d[0] = bf16r(v.x); d[1] = bf16r(v.y); d[2] = bf16r(v.z); d[3] = bf16r(v.w);
    }
    if (tid < 32) facc[tid] = 0.f;
    __syncthreads();

    float s_[2][4] = {{0.f,0.f,0.f,0.f},{0.f,0.f,0.f,0.f}};
    const int colbase = wv * 256;

    for (int sub = 0; sub < 16; ++sub) {
        const int col = colbase + sub * 16 + l15;
        f32x4 acc0 = {0.f,0.f,0.f,0.f}, acc1 = {0.f,0.f,0.f,0.f};
        const unsigned short* bp = w1bT + (size_t)col * DF + quad * 8;
        const unsigned short* a0p = &xs[l15 * XROW + quad * 8];
        const unsigned short* a1p = &xs[(16 + l15) * XROW + quad * 8];
#pragma unroll
        for (int t = 0; t < 16; ++t) {
            bf16x8 bfrag = *(const bf16x8*)(bp + t * 32);
            bf16x8 a0 = *(const bf16x8*)(a0p + t * 32);
            bf16x8 a1 = *(const bf16x8*)(a1p + t * 32);
            acc0 = __builtin_amdgcn_mfma_f32_16x16x32_bf16(a0, bfrag, acc0, 0, 0, 0);
            acc1 = __builtin_amdgcn_mfma_f32_16x16x32_bf16(a1, bfrag, acc1, 0, 0, 0);
        }
        const float b1c = b1[col], w2c = w2[col];
#pragma unroll
        for (int r = 0; r < 4; ++r) {
            float h0 = acc0[r] + b1c; h0 = h0 > 0.f ? h0 : 0.f; s_[0][r] = fmaf(h0, w2c, s_[0][r]);
            float h1 = acc1[r] + b1c; h1 = h1 > 0.f ? h1 : 0.f; s_[1][r] = fmaf(h1, w2c, s_[1][r]);
        }
    }
    // reduce the 16 col-lanes within each quad; C row = quad*4 + r
#pragma unroll
    for (int q = 0; q < 2; ++q)
#pragma unroll
        for (int r = 0; r < 4; ++r) {
            float v = s_[q][r];
            v += __shfl_xor(v, 1, 16);
            v += __shfl_xor(v, 2, 16);
            v += __shfl_xor(v, 4, 16);
            v += __shfl_xor(v, 8, 16);
            if (l15 == 0) atomicAdd(&facc[q * 16 + quad * 4 + r], v);
        }
    __syncthreads();
    if (tid < 32) {
        float z = facc[tid] + b2[0];
        fout[n0 + tid] = 1.f / (1.f + expf(-z));
    }
}

// ---------------- Stage 1 legacy (fp32 VALU) — ws_size fallback -----------
#define TN2 16
__global__ __launch_bounds__(256) void k_fil(
    const float* __restrict__ x, const float* __restrict__ w1,
    const float* __restrict__ b1, const float* __restrict__ w2,
    const float* __restrict__ b2, float* __restrict__ fout)
{
    __shared__ float xs[TN2][DF];
    __shared__ float part[256];
    const int tid = threadIdx.x;
    const int n0 = blockIdx.x * TN2;
    for (int c = tid; c < TN2 * DF / 4; c += 256) {
        int n = c >> 7, k4 = (c & 127) << 2;
        *(float4*)&xs[n][k4] = *(const float4*)(x + (size_t)(n0 + n) * DF + k4);
    }
    __syncthreads();
    float h[TN2][4];
#pragma unroll
    for (int n = 0; n < TN2; ++n)
#pragma unroll
        for (int q = 0; q < 4; ++q) h[n][q] = 0.f;
    for (int k = 0; k < DF; ++k) {
        float wr[4];
#pragma unroll
        for (int q = 0; q < 4; ++q) wr[q] = w1[(size_t)k * HF + tid + 256 * q];
#pragma unroll
        for (int n = 0; n < TN2; ++n) {
            float xv = xs[n][k];
#pragma unroll
            for (int q = 0; q < 4; ++q) h[n][q] = fmaf(xv, wr[q], h[n][q]);
        }
    }
    float b1r[4], w2r[4];
#pragma unroll
    for (int q = 0; q < 4; ++q) { b1r[q] = b1[tid + 256 * q]; w2r[q] = w2[tid + 256 * q]; }
    const float b2v = b2[0];
    for (int n = 0; n < TN2; ++n) {
        float s = 0.f;
#pragma unroll
        for (int q = 0; q < 4; ++q) {
            float hv = h[n][q] + b1r[q];
            s += (hv > 0.f ? hv : 0.f) * w2r[q];
        }
        part[tid] = s;
        __syncthreads();
        for (int off = 128; off > 0; off >>= 1) {
            if (tid < off) part[tid] += part[tid + off];
            __syncthreads();
        }
        if (tid == 0) fout[n0 + n] = 1.f / (1.f + expf(-(part[0] + b2v)));
        __syncthreads();
    }
}

// ------------- Stage 2: 0-dim persistence via Boruvka MST filter ----------
// (unchanged from R9 — bit-exact verified)
__global__ __launch_bounds__(256) void k_pers(
    const int* __restrict__ edges, const float* __restrict__ fbuf,
    float* __restrict__ dout /* [2][NTOT] */)
{
    const int bid = blockIdx.x;
    const int g = bid >> 1, sgn = bid & 1;
    const int tid = threadIdx.x;

    __shared__ float fv[NODES];
    __shared__ unsigned long long vkey[NODES];
    __shared__ int order_[NODES], rank_[NODES];
    __shared__ float fvr[NODES];
    __shared__ unsigned eks[EDGES];
    __shared__ int comp[NODES];
    __shared__ unsigned minE[NODES];
    __shared__ int nxt[NODES], par2[NODES];
    __shared__ unsigned char mstflag[EDGES];
    __shared__ int cnt;
    __shared__ unsigned mstK[NODES];
    __shared__ int par[NODES], dr[NODES], cmaxr[NODES];

    float f0 = fbuf[g * NODES + tid];
    fv[tid] = sgn ? -f0 : f0;
    vkey[tid] = ((unsigned long long)encf(fv[tid]) << 32) | (unsigned)tid;
    __syncthreads();

    for (int k = 2; k <= NODES; k <<= 1)
        for (int j = k >> 1; j > 0; j >>= 1) {
            int i = tid, ixj = i ^ j;
            if (ixj > i) {
                unsigned long long a = vkey[i], b = vkey[ixj];
                bool up = ((i & k) == 0);
                if ((a > b) == up) { vkey[i] = b; vkey[ixj] = a; }
            }
            __syncthreads();
        }

    int ov = (int)(unsigned)(vkey[tid] & 0xFFFFFFFFULL);
    order_[tid] = ov;
    rank_[ov] = tid;
    fvr[tid] = fv[ov];
    comp[tid] = tid;
    __syncthreads();

#pragma unroll
    for (int q = 0; q < 4; ++q) {
        int e = tid + q * 256;
        int u = edges[2 * (g * EDGES + e)]     - g * NODES;
        int v = edges[2 * (g * EDGES + e) + 1] - g * NODES;
        if (u == v) { eks[e] = INF32; }
        else {
            int ra = rank_[u], rb = rank_[v];
            int rlo = ra < rb ? ra : rb, rhi = ra < rb ? rb : ra;
            eks[e] = ((unsigned)rhi << 18) | ((unsigned)e << 8) | (unsigned)rlo;
        }
        mstflag[e] = 0;
    }
    __syncthreads();

    for (int round = 0; round < 8; ++round) {
        minE[tid] = INF32;
        __syncthreads();
#pragma unroll
        for (int q = 0; q < 4; ++q) {
            unsigned k = eks[tid + q * 256];
            if (k != INF32) {
                int rlo = (int)(k & 255u), rhi = (int)(k >> 18);
                int cu = comp[rlo], cv = comp[rhi];
                if (cu != cv) {
                    atomicMin(&minE[cu], k);
                    atomicMin(&minE[cv], k);
                }
            }
        }
        __syncthreads();
        {
            unsigned mk = minE[tid];
            int o = tid;
            if (mk != INF32) {
                int rlo = (int)(mk & 255u), rhi = (int)(mk >> 18);
                int cu = comp[rlo], cv = comp[rhi];
                o = (cu == tid) ? cv : cu;
                mstflag[(mk >> 8) & 0x3FFu] = 1;
            }
            nxt[tid] = o;
        }
        __syncthreads();
        {
            int o = nxt[tid];
            int p = o;
            if (nxt[o] == tid && tid < o) p = tid;
            par2[tid] = p;
        }
        __syncthreads();
        for (int j = 0; j < 8; ++j) {
            int p = par2[par2[tid]];
            __syncthreads();
            par2[tid] = p;
            __syncthreads();
        }
        comp[tid] = par2[comp[tid]];
        __syncthreads();
    }

    if (tid == 0) cnt = 0;
    __syncthreads();
#pragma unroll
    for (int q = 0; q < 4; ++q) {
        int e = tid + q * 256;
        if (mstflag[e]) {
            int p = atomicAdd(&cnt, 1);
            mstK[p] = eks[e];
        }
    }
    __syncthreads();
    if (tid >= cnt) mstK[tid] = INF32;
    __syncthreads();

    for (int k = 2; k <= NODES; k <<= 1)
        for (int j = k >> 1; j > 0; j >>= 1) {
            int i = tid, ixj = i ^ j;
            if (ixj > i) {
                unsigned a = mstK[i], b = mstK[ixj];
                bool up = ((i & k) == 0);
                if ((a > b) == up) { mstK[i] = b; mstK[ixj] = a; }
            }
            __syncthreads();
        }

    par[tid] = tid; dr[tid] = -1; cmaxr[tid] = 0;
    __syncthreads();

    if (tid == 0) {
        for (int s = 0; s < NODES; ++s) {
            unsigned k = mstK[s];
            if (k == INF32) break;
            int rlo = (int)(k & 255u), rhi = (int)(k >> 18);
            int a = rlo; while (par[a] != a) { par[a] = par[par[a]]; a = par[a]; }
            int b = rhi; while (par[b] != b) { par[b] = par[par[b]]; b = par[b]; }
            if (a != b) {
                int elder = a < b ? a : b, young = a < b ? b : a;
                par[young] = elder;
                dr[young] = rhi;
            }
        }
    }
    __syncthreads();

    int r = tid;
    while (par[r] != r) r = par[r];
    atomicMax(&cmaxr[r], tid);
    __syncthreads();

    float dv = (dr[tid] >= 0) ? fvr[dr[tid]] : fvr[cmaxr[r]];
    dout[sgn * NTOT + g * NODES + order_[tid]] = dv;
}

// ------- Stage 3: per-pair MLPs + segment sum + linear head (fused) -------
__global__ __launch_bounds__(256) void k_head(
    const float* __restrict__ fbuf, const float* __restrict__ dbuf,
    const float* __restrict__ wp0, const float* __restrict__ bp0,
    const float* __restrict__ wp1, const float* __restrict__ bp1,
    const float* __restrict__ wh, const float* __restrict__ bh,
    float* __restrict__ out)
{
    const int g = blockIdx.x, tid = threadIdx.x;
    __shared__ float lf[NODES], l0[NODES], l1[NODES];
    __shared__ float sp0[NODES], sp1[NODES];
    lf[tid] = fbuf[g * NODES + tid];
    l0[tid] = dbuf[g * NODES + tid];
    l1[tid] = dbuf[NTOT + g * NODES + tid];
    __syncthreads();
    const float w00 = wp0[tid], w01 = wp0[HP + tid], bb0 = bp0[tid];
    const float w10 = wp1[tid], w11 = wp1[HP + tid], bb1 = bp1[tid];
    float s0 = 0.f, s1 = 0.f;
    for (int n = 0; n < NODES; ++n) {
        float f = lf[n], d0 = l0[n], d1 = l1[n];
        float a0 = fmaf(f, w00, fmaf(d0, w01, bb0));      // h0 = (f, d_sub)
        float a1 = fmaf(-d1, w10, fmaf(f, w11, bb1));     // h1 = (-d_sup, f)
        s0 += a0 > 0.f ? a0 : 0.f;
        s1 += a1 > 0.f ? a1 : 0.f;
    }
    sp0[tid] = s0; sp1[tid] = s1;
    __syncthreads();
    if (tid < NC) {
        float acc = bh[tid];
        for (int j = 0; j < HP; ++j)
            acc += sp0[j] * wh[j * NC + tid] + sp1[j] * wh[(HP + j) * NC + tid];
        out[g * NC + tid] = acc;   // f32 output (reference dtype)
    }
}

extern "C" void kernel_launch(void* const* d_in, const int* in_sizes, int n_in,
                              void* d_out, int out_size, void* d_ws, size_t ws_size,
                              hipStream_t stream)
{
    const float* x   = (const float*)d_in[0];
    const int*   edg = (const int*)d_in[1];
    const float* w1  = (const float*)d_in[3];
    const float* b1  = (const float*)d_in[4];
    const float* w2  = (const float*)d_in[5];
    const float* b2  = (const float*)d_in[6];
    const float* wp0 = (const float*)d_in[7];
    const float* bp0 = (const float*)d_in[8];
    const float* wp1 = (const float*)d_in[9];
    const float* bp1 = (const float*)d_in[10];
    const float* wh  = (const float*)d_in[11];
    const float* bh  = (const float*)d_in[12];

    float* fbuf = (float*)d_ws;                       // [NTOT] f32
    float* dbuf = fbuf + NTOT;                        // [2][NTOT] f32
    unsigned short* w1bT = (unsigned short*)(dbuf + 2 * NTOT);  // [HF][DF] bf16

    const size_t WS_REQ = (size_t)NTOT * 4 + (size_t)2 * NTOT * 4
                        + (size_t)HF * DF * 2 + 256;

    if (ws_size >= WS_REQ) {
        k_cvtT    <<<512, 256, 0, stream>>>(w1, w1bT);
        k_fil_mfma<<<NTOT / 32, 256, 0, stream>>>(x, w1bT, b1, w2, b2, fbuf);
    } else {
        k_fil     <<<NTOT / TN2, 256, 0, stream>>>(x, w1, b1, w2, b2, fbuf);
    }
    k_pers<<<NUM_GRAPHS * 2, 256, 0, stream>>>(edg, fbuf, dbuf);
    k_head<<<NUM_GRAPHS, 256, 0, stream>>>(fbuf, dbuf, wp0, bp0, wp1, bp1, wh, bh,
                                           (float*)d_out);
}